// Round 8
// baseline (9008.983 us; speedup 1.0000x reference)
//
#include <hip/hip_runtime.h>

// ---------------------------------------------------------------------------
// VRAE LSTM: B=512, T=512, HE=HD=512, L=64.
// 32 groups (16 rows) x 8 WGs (64 units, 512 thr, 8 waves). Single 16-row
// phase per step: spin(gen-tag) -> LDS -> 1 bar -> 32 MFMA -> lane-transpose
// -> ew(2 rows/lane) -> store -> prefetch -> heads. U packed f16 in ws,
// asm-loaded (resident). h: gen-tagged u32 (gen16|f16) double buffer via
// relaxed agent atomics (XCD-local exchange through local L2).
// ---------------------------------------------------------------------------

#define B_ 512
#define T_ 512
#define H_ 512

typedef _Float16 f16;
typedef _Float16 f16x8 __attribute__((ext_vector_type(8)));
typedef float f32x16 __attribute__((ext_vector_type(16)));
typedef unsigned long long u64;
typedef unsigned int u32;

// d_out floats: mu_dec[512*512] | sg_dec[512*512] | mu_enc[512*64] | sg_enc[512*64]
#define OFF_SG_DEC 262144
#define OFF_MU_ENC 524288
#define OFF_SG_ENC 557056

__device__ __forceinline__ float sigm_(float x) { return 1.f / (1.f + __expf(-x)); }
__device__ __forceinline__ float tanh_(float x) {
  float t = fabsf(x);
  float e = __expf(2.f * t);
  float r = 1.f - 2.f / (e + 1.f);
  return x < 0.f ? -r : r;
}
__device__ __forceinline__ float softplus_(float x) {
  return fmaxf(x, 0.f) + log1pf(__expf(-fabsf(x)));
}
__device__ __forceinline__ int fresh_(u64 w, u32 g) {
  return ((u32)(w >> 48) == g) & (((u32)(w >> 16) & 0xffffu) == g);
}
__device__ __forceinline__ u32 packh_(u64 w) {
  return (u32)(w & 0xffffu) | (((u32)(w >> 32) & 0xffffu) << 16);
}

// ---------------------------------------------------------------------------
__global__ void pack_U(const float* __restrict__ U, f16* __restrict__ Upk) {
  const int e = blockIdx.x * 256 + threadIdx.x;  // 2^20 elements
  const int j = e & 7, lane = (e >> 3) & 63, ks = (e >> 9) & 31;
  const int w = (e >> 14) & 7, wg = (e >> 17) & 7;
  const int ccol = lane & 31, khalf = lane >> 5;
  const int uu = ccol >> 2, gate = ccol & 3;
  const int k = ks * 16 + khalf * 8 + j;
  const int gcol = gate * 512 + wg * 64 + w * 8 + uu;
  Upk[e] = (f16)U[k * 2048 + gcol];
}

// ---------------------------------------------------------------------------
// IS_DEC=0: xin=[B][T] input, wa=enc_W, wb=enc_b
// IS_DEC=1: xin=zin [B][2048] (bias folded), wa=dmu_W, wb=dstd_W
// ---------------------------------------------------------------------------
template <int IS_DEC>
__global__ void __launch_bounds__(512, 1)
lstm_rec(const f16* __restrict__ Upk,
         const float* __restrict__ xin,
         const float* __restrict__ wa,
         const float* __restrict__ wb,
         u32* __restrict__ hbuf,
         float* __restrict__ accmu,
         float* __restrict__ accsg) {
  const int bid = blockIdx.x;
  const int s = bid >> 3;
  const int g = (bid & 7) * 4 + (s & 3);  // group 0..31 (8 WGs share bid%8 -> XCD)
  const int wg = s >> 2;                  // unit slice 0..7
  const int tid = threadIdx.x, wave = tid >> 6, lane = tid & 63;
  const int U0 = wg * 64;
  const int R0 = g * 16;
  const u32 GB = IS_DEC ? 0x8000u : 0u;
  const int ccol = lane & 31, khalf = lane >> 5;

  // ---- Breg from packed U (asm volatile: resident, non-remat) -------------
  f16x8 Breg[32];
#pragma unroll
  for (int ks = 0; ks < 32; ++ks) {
    const f16* p = Upk + (((wg * 8 + wave) * 32 + ks) << 9) + lane * 8;
    asm volatile("global_load_dwordx4 %0, %1, off\n\ts_waitcnt vmcnt(0)"
                 : "=v"(Breg[ks]) : "v"(p));
  }

  // ---- lane ew ownership: rows r_lo, r_hi (=r_lo+8); unit unit_l ----------
  const int p_ = ccol & 3, uu_ = ccol >> 2;
  const int r_lo = p_ + 4 * khalf, r_hi = r_lo + 8;
  const int unit_l = wave * 8 + uu_;
  float biasv[4], xwv[4], addLo[4], addHi[4];
#pragma unroll
  for (int gt = 0; gt < 4; ++gt) {
    const int col = gt * 512 + U0 + unit_l;
    if (IS_DEC) {
      addLo[gt] = xin[(R0 + r_lo) * 2048 + col];
      addHi[gt] = xin[(R0 + r_hi) * 2048 + col];
      biasv[gt] = 0.f; xwv[gt] = 0.f;
    } else {
      biasv[gt] = wb[col];
      xwv[gt] = wa[col];
      addLo[gt] = 0.f; addHi[gt] = 0.f;
    }
  }
  // per-WG head rows: 2*wg (wave 0), 2*wg+1 (wave 1)
  float wmu[8], wsg[8];
  if (IS_DEC) {
#pragma unroll
    for (int q = 0; q < 8; ++q) {
      wmu[q] = wa[lane * 8 + q];
      wsg[q] = wb[lane * 8 + q];
    }
  }

  float cLo = 0.f, cHi = 0.f;

  __shared__ __align__(16) f16 bufs[2][16 * 520];   // 2 x 16,640 B
  __shared__ float xl[16 * 516];                    // 33,024 B (encoder x)

  if (!IS_DEC) {
#pragma unroll
    for (int i = 0; i < 16; ++i) {
      const int idx = tid + i * 512;
      const int r = idx >> 9, c2 = idx & 511;
      xl[r * 516 + c2] = xin[(R0 + r) * T_ + c2];
    }
  }

  // staging: 8 u64/thread of the [16 rows][256 u64] tile
  int srow[8], scol[8], gidx[8];
#pragma unroll
  for (int i = 0; i < 8; ++i) {
    const int w = tid + i * 512;
    srow[i] = w >> 8; scol[i] = w & 255;
    gidx[i] = (R0 + srow[i]) * 256 + scol[i];
  }
  const u64* hb64 = (const u64*)hbuf;

  u64 wr[8];
#pragma unroll
  for (int i = 0; i < 8; ++i)
    wr[i] = __hip_atomic_load(hb64 + gidx[i], __ATOMIC_RELAXED,
                              __HIP_MEMORY_SCOPE_AGENT);
  asm volatile("" ::: "memory");

  for (int t = 0; t < T_; ++t) {
    const int b0 = (t & 1) * 131072;          // u64 offset, read buffer
    const int b1 = ((t + 1) & 1) * 131072;    // u64 offset, next buffer
    const int c1 = ((t + 1) & 1) * 262144;    // u32 offset, write buffer
    const u32 gr = GB + (u32)t, gn = gr + 1u;

    // ---- spin until all 8 words fresh ----
    for (;;) {
      int f = 1;
#pragma unroll
      for (int i = 0; i < 8; ++i) f &= fresh_(wr[i], gr);
      if (f) break;
#pragma unroll
      for (int i = 0; i < 8; ++i)
        wr[i] = __hip_atomic_load(hb64 + b0 + gidx[i], __ATOMIC_RELAXED,
                                  __HIP_MEMORY_SCOPE_AGENT);
    }
    f16* const sb = bufs[t & 1];
#pragma unroll
    for (int i = 0; i < 8; ++i)
      *(u32*)&sb[srow[i] * 520 + scol[i] * 2] = packh_(wr[i]);
    __syncthreads();  // the only barrier per step

    // ---- gates = h @ U (32 MFMA, 16 rows live) ----
    f32x16 acc;
#pragma unroll
    for (int q = 0; q < 16; ++q) acc[q] = 0.f;
#pragma unroll
    for (int ks = 0; ks < 32; ++ks) {
      f16x8 a = *(const f16x8*)&sb[(lane & 15) * 520 + ks * 16 + khalf * 8];
      acc = __builtin_amdgcn_mfma_f32_32x32x16_f16(a, Breg[ks], acc, 0, 0, 0);
    }

    // ---- 4x4 lane transposes: acc[0..3] -> row r_lo ; acc[4..7] -> r_hi ----
    const int odd1 = lane & 1, odd2 = lane & 2;
    float gLo0, gLo1, gLo2, gLo3, gHi0, gHi1, gHi2, gHi3;
    {
      const float x0 = acc[0], x1 = acc[1], x2 = acc[2], x3 = acc[3];
      const float t0 = __shfl_xor(x1, 1), t1 = __shfl_xor(x0, 1);
      const float t2 = __shfl_xor(x3, 1), t3 = __shfl_xor(x2, 1);
      const float y0 = odd1 ? t0 : x0, y1 = odd1 ? x1 : t1;
      const float y2 = odd1 ? t2 : x2, y3 = odd1 ? x3 : t3;
      const float s0 = __shfl_xor(y2, 2), s1 = __shfl_xor(y3, 2);
      const float s2 = __shfl_xor(y0, 2), s3 = __shfl_xor(y1, 2);
      gLo0 = odd2 ? s0 : y0; gLo1 = odd2 ? s1 : y1;
      gLo2 = odd2 ? y2 : s2; gLo3 = odd2 ? y3 : s3;
    }
    {
      const float x0 = acc[4], x1 = acc[5], x2 = acc[6], x3 = acc[7];
      const float t0 = __shfl_xor(x1, 1), t1 = __shfl_xor(x0, 1);
      const float t2 = __shfl_xor(x3, 1), t3 = __shfl_xor(x2, 1);
      const float y0 = odd1 ? t0 : x0, y1 = odd1 ? x1 : t1;
      const float y2 = odd1 ? t2 : x2, y3 = odd1 ? x3 : t3;
      const float s0 = __shfl_xor(y2, 2), s1 = __shfl_xor(y3, 2);
      const float s2 = __shfl_xor(y0, 2), s3 = __shfl_xor(y1, 2);
      gHi0 = odd2 ? s0 : y0; gHi1 = odd2 ? s1 : y1;
      gHi2 = odd2 ? y2 : s2; gHi3 = odd2 ? y3 : s3;
    }

    // ---- elementwise, 2 rows per lane ----
    float hnLo, hnHi;
    {
      float ga0, ga1, ga2, ga3;
      if (IS_DEC) {
        ga0 = gLo0 + addLo[0]; ga1 = gLo1 + addLo[1];
        ga2 = gLo2 + addLo[2]; ga3 = gLo3 + addLo[3];
      } else {
        const float xv = xl[r_lo * 516 + t];
        ga0 = gLo0 + biasv[0] + xv * xwv[0];
        ga1 = gLo1 + biasv[1] + xv * xwv[1];
        ga2 = gLo2 + biasv[2] + xv * xwv[2];
        ga3 = gLo3 + biasv[3] + xv * xwv[3];
      }
      const float cn = sigm_(ga1) * cLo + sigm_(ga0) * tanh_(ga2);
      cLo = cn;
      hnLo = sigm_(ga3) * tanh_(cn);
    }
    {
      float ga0, ga1, ga2, ga3;
      if (IS_DEC) {
        ga0 = gHi0 + addHi[0]; ga1 = gHi1 + addHi[1];
        ga2 = gHi2 + addHi[2]; ga3 = gHi3 + addHi[3];
      } else {
        const float xv = xl[r_hi * 516 + t];
        ga0 = gHi0 + biasv[0] + xv * xwv[0];
        ga1 = gHi1 + biasv[1] + xv * xwv[1];
        ga2 = gHi2 + biasv[2] + xv * xwv[2];
        ga3 = gHi3 + biasv[3] + xv * xwv[3];
      }
      const float cn = sigm_(ga1) * cHi + sigm_(ga0) * tanh_(ga2);
      cHi = cn;
      hnHi = sigm_(ga3) * tanh_(cn);
    }

    // ---- h stores (gen-tagged) ----
    {
      union { f16 h; unsigned short u; } a, b;
      a.h = (f16)hnLo; b.h = (f16)hnHi;
      __hip_atomic_store(hbuf + c1 + (R0 + r_lo) * 512 + U0 + unit_l,
                         (gn << 16) | (u32)a.u, __ATOMIC_RELAXED,
                         __HIP_MEMORY_SCOPE_AGENT);
      __hip_atomic_store(hbuf + c1 + (R0 + r_hi) * 512 + U0 + unit_l,
                         (gn << 16) | (u32)b.u, __ATOMIC_RELAXED,
                         __HIP_MEMORY_SCOPE_AGENT);
    }

    // ---- prefetch next step (producers just stored ~now) ----
#pragma unroll
    for (int i = 0; i < 8; ++i)
      wr[i] = __hip_atomic_load(hb64 + b1 + gidx[i], __ATOMIC_RELAXED,
                                __HIP_MEMORY_SCOPE_AGENT);
    asm volatile("" ::: "memory");

    // ---- decoder heads for output t-1 (rows 2wg, 2wg+1), off-chain ----
    if (IS_DEC && t >= 1 && wave < 2) {
      const int hr = 2 * wg + wave;
      const f16x8 hv = *(const f16x8*)&sb[hr * 520 + lane * 8];
      float smu = 0.f, ssg = 0.f;
#pragma unroll
      for (int q = 0; q < 8; ++q) {
        const float hq = (float)hv[q];
        smu += hq * wmu[q]; ssg += hq * wsg[q];
      }
#pragma unroll
      for (int o = 32; o; o >>= 1) {
        smu += __shfl_xor(smu, o); ssg += __shfl_xor(ssg, o);
      }
      if (lane == 0) {
        accmu[(R0 + hr) * 512 + (t - 1)] = smu;
        accsg[(R0 + hr) * 512 + (t - 1)] = ssg;
      }
    }
  }
}

// ---------------------------------------------------------------------------
// Decoder tail: mu/sg[., 511] from final h (buffer 0).
// ---------------------------------------------------------------------------
__global__ void dec_tail(const u32* __restrict__ hbuf, const float* __restrict__ dmuW,
                         const float* __restrict__ dstdW, float* __restrict__ accmu,
                         float* __restrict__ accsg) {
  const int r = blockIdx.x, lane = threadIdx.x;  // 64 threads
  float smu = 0.f, ssg = 0.f;
#pragma unroll
  for (int q = 0; q < 8; ++q) {
    union { unsigned short u; f16 h; } c;
    c.u = (unsigned short)(hbuf[r * 512 + lane * 8 + q] & 0xffffu);
    const float hq = (float)c.h;
    smu += hq * dmuW[lane * 8 + q];
    ssg += hq * dstdW[lane * 8 + q];
  }
#pragma unroll
  for (int o = 32; o; o >>= 1) {
    smu += __shfl_xor(smu, o); ssg += __shfl_xor(ssg, o);
  }
  if (lane == 0) {
    accmu[r * 512 + 511] = smu;
    accsg[r * 512 + 511] = ssg;
  }
}

// ---------------------------------------------------------------------------
__global__ void enc_heads(const u32* __restrict__ h0, const float* __restrict__ emuW,
                          const float* __restrict__ emub, const float* __restrict__ estdW,
                          const float* __restrict__ estdb, float* __restrict__ out,
                          float* __restrict__ z) {
  const int b = blockIdx.x, tid = threadIdx.x;
  __shared__ float hrow[512];
  for (int k = tid; k < 512; k += 128) {
    union { unsigned short u; f16 h; } c;
    c.u = (unsigned short)(h0[b * 512 + k] & 0xffffu);
    hrow[k] = (float)c.h;
  }
  __syncthreads();
  const int head = tid >> 6, l = tid & 63;
  const float* W = head ? estdW : emuW;
  float a = 0.f;
#pragma unroll 8
  for (int k = 0; k < 512; ++k) a += hrow[k] * W[k * 64 + l];
  if (head == 0) {
    const float v = a + emub[l];
    out[OFF_MU_ENC + b * 64 + l] = v;
    z[b * 64 + l] = v;
  } else {
    out[OFF_SG_ENC + b * 64 + l] = softplus_(a + estdb[l]);
  }
}

// ---------------------------------------------------------------------------
__global__ void dec_prep(const float* __restrict__ z, const float* __restrict__ dfsW,
                         const float* __restrict__ dfsb, const float* __restrict__ decW,
                         const float* __restrict__ decb, u32* __restrict__ hbuf,
                         float* __restrict__ zin) {
  const int b = blockIdx.x, tid = threadIdx.x;
  __shared__ float zl[64];
  if (tid < 64) zl[tid] = z[b * 64 + tid];
  __syncthreads();
  for (int c = tid; c < 512; c += 256) {
    float a = dfsb[c];
#pragma unroll
    for (int l = 0; l < 64; ++l) a += zl[l] * dfsW[l * 512 + c];
    union { f16 h; unsigned short u; } hc; hc.h = (f16)tanh_(a);
    hbuf[b * 512 + c] = (0x8000u << 16) | (u32)hc.u;
  }
  for (int c = tid; c < 2048; c += 256) {
    float a = decb[c];
#pragma unroll
    for (int l = 0; l < 64; ++l) a += zl[l] * decW[l * 2048 + c];
    zin[b * 2048 + c] = a;
  }
}

// ---------------------------------------------------------------------------
__global__ void finalize_k(const float* __restrict__ accmu, const float* __restrict__ accsg,
                           const float* __restrict__ dmub, const float* __restrict__ dstdb,
                           float* __restrict__ out) {
  const int i = blockIdx.x * 256 + threadIdx.x;
  out[i] = accmu[i] + dmub[0];
  out[OFF_SG_DEC + i] = softplus_(accsg[i] + dstdb[0]);
}

// ---------------------------------------------------------------------------
extern "C" void kernel_launch(void* const* d_in, const int* in_sizes, int n_in,
                              void* d_out, int out_size, void* d_ws, size_t ws_size,
                              hipStream_t stream) {
  (void)in_sizes; (void)n_in; (void)out_size; (void)ws_size;
  const float* x     = (const float*)d_in[0];
  const float* encW  = (const float*)d_in[1];
  const float* encU  = (const float*)d_in[2];
  const float* encb  = (const float*)d_in[3];
  const float* emuW  = (const float*)d_in[4];
  const float* emub  = (const float*)d_in[5];
  const float* estdW = (const float*)d_in[6];
  const float* estdb = (const float*)d_in[7];
  const float* dfsW  = (const float*)d_in[8];
  const float* dfsb  = (const float*)d_in[9];
  const float* decW  = (const float*)d_in[10];
  const float* decU  = (const float*)d_in[11];
  const float* decb  = (const float*)d_in[12];
  const float* dmuW  = (const float*)d_in[13];
  const float* dmub  = (const float*)d_in[14];
  const float* dstdW = (const float*)d_in[15];
  const float* dstdb = (const float*)d_in[16];

  char* ws = (char*)d_ws;
  u32*   hbuf  = (u32*)(ws + 0);                   // 2 MB: [2][512][512] u32
  float* accmu = (float*)(ws + (2u << 20));        // 1 MB
  float* accsg = (float*)(ws + (3u << 20));        // 1 MB
  f16*   UpkE  = (f16*)(ws + (4u << 20));          // 2 MB (dead after encoder)
  float* zin   = (float*)(ws + (4u << 20));        // 4 MB (overlays UpkE)
  f16*   UpkD  = (f16*)(ws + (8u << 20));          // 2 MB
  float* z     = (float*)(ws + (10u << 20));       // 128 KB
  float* out   = (float*)d_out;

  // zero hbuf (gen tags) every launch; acc fully rewritten by heads+tail.
  hipMemsetAsync(d_ws, 0, 2u << 20, stream);

  hipLaunchKernelGGL(pack_U, dim3(4096), dim3(256), 0, stream, encU, UpkE);
  hipLaunchKernelGGL(pack_U, dim3(4096), dim3(256), 0, stream, decU, UpkD);

  hipLaunchKernelGGL((lstm_rec<0>), dim3(256), dim3(512), 0, stream,
                     UpkE, x, encW, encb, hbuf, (float*)nullptr, (float*)nullptr);
  hipLaunchKernelGGL(enc_heads, dim3(512), dim3(128), 0, stream,
                     hbuf, emuW, emub, estdW, estdb, out, z);
  hipLaunchKernelGGL(dec_prep, dim3(512), dim3(256), 0, stream,
                     z, dfsW, dfsb, decW, decb, hbuf, zin);
  hipLaunchKernelGGL((lstm_rec<1>), dim3(256), dim3(512), 0, stream,
                     UpkD, zin, dmuW, dstdW, hbuf, accmu, accsg);
  hipLaunchKernelGGL(dec_tail, dim3(512), dim3(64), 0, stream,
                     hbuf, dmuW, dstdW, accmu, accsg);
  hipLaunchKernelGGL(finalize_k, dim3(1024), dim3(256), 0, stream,
                     accmu, accsg, dmub, dstdb, out);
}

// Round 9
// 4999.200 us; speedup vs baseline: 1.8021x; 1.8021x over previous
//
#include <hip/hip_runtime.h>

// ---------------------------------------------------------------------------
// VRAE LSTM: B=512, T=512, HE=HD=512, L=64.
// Round 9 = round-6 structure (the measured-best recurrent kernel) with the
// decoder's contended atomics replaced by per-wave head reductions from the
// staged LDS h tile (duplicated across the pair's 8 WGs; plain stores).
// 32 pairs (16 rows: A=8,B=8) x 8 unit-slice WGs (512 thr). U packed f16,
// asm-loaded (resident). h: gen-tagged u32 (gen16|f16) double buffer via
// relaxed agent atomics; consumers spin on the tag. A/B phase interleave
// hides store/load RTT.
// ---------------------------------------------------------------------------

#define B_ 512
#define T_ 512
#define H_ 512

typedef _Float16 f16;
typedef _Float16 f16x8 __attribute__((ext_vector_type(8)));
typedef float f32x16 __attribute__((ext_vector_type(16)));
typedef unsigned long long u64;
typedef unsigned int u32;

// d_out floats: mu_dec[512*512] | sg_dec[512*512] | mu_enc[512*64] | sg_enc[512*64]
#define OFF_SG_DEC 262144
#define OFF_MU_ENC 524288
#define OFF_SG_ENC 557056

__device__ __forceinline__ float sigm_(float x) { return 1.f / (1.f + __expf(-x)); }
__device__ __forceinline__ float tanh_(float x) {
  float t = fabsf(x);
  float e = __expf(2.f * t);
  float r = 1.f - 2.f / (e + 1.f);
  return x < 0.f ? -r : r;
}
__device__ __forceinline__ float softplus_(float x) {
  return fmaxf(x, 0.f) + log1pf(__expf(-fabsf(x)));
}
__device__ __forceinline__ int fresh_(u64 w, u32 g) {
  return ((u32)(w >> 48) == g) & (((u32)(w >> 16) & 0xffffu) == g);
}
__device__ __forceinline__ u32 packh_(u64 w) {
  return (u32)(w & 0xffffu) | (((u32)(w >> 32) & 0xffffu) << 16);
}

// ---------------------------------------------------------------------------
__global__ void pack_U(const float* __restrict__ U, f16* __restrict__ Upk) {
  const int e = blockIdx.x * 256 + threadIdx.x;  // 2^20 elements
  const int j = e & 7, lane = (e >> 3) & 63, ks = (e >> 9) & 31;
  const int w = (e >> 14) & 7, wg = (e >> 17) & 7;
  const int ccol = lane & 31, khalf = lane >> 5;
  const int uu = ccol >> 2, gate = ccol & 3;
  const int k = ks * 16 + khalf * 8 + j;
  const int gcol = gate * 512 + wg * 64 + w * 8 + uu;
  Upk[e] = (f16)U[k * 2048 + gcol];
}

// ---------------------------------------------------------------------------
// IS_DEC=0: xin=[B][T] input, wa=enc_W, wb=enc_b
// IS_DEC=1: xin=zin [B][2048] (bias folded), wa=dmu_W, wb=dstd_W
// ---------------------------------------------------------------------------
template <int IS_DEC>
__global__ void __launch_bounds__(512, 1)
lstm_rec(const f16* __restrict__ Upk,
         const float* __restrict__ xin,
         const float* __restrict__ wa,
         const float* __restrict__ wb,
         u32* __restrict__ hbuf,
         float* __restrict__ accmu,
         float* __restrict__ accsg) {
  const int bid = blockIdx.x;
  const int s = bid >> 3;
  const int j = (bid & 7) * 4 + (s & 3);  // row-pair 0..31 (XCD-local)
  const int wg = s >> 2;                  // unit slice 0..7
  const int tid = threadIdx.x, wave = tid >> 6, lane = tid & 63;
  const int U0 = wg * 64;
  const int RA = j * 16, RB = j * 16 + 8;
  const u32 GB = IS_DEC ? 0x8000u : 0u;
  const int ccol = lane & 31, khalf = lane >> 5;

  // ---- Breg from packed U (asm volatile: cannot be rematerialized) --------
  f16x8 Breg[32];
#pragma unroll
  for (int ks = 0; ks < 32; ++ks) {
    const f16* p = Upk + (((wg * 8 + wave) * 32 + ks) << 9) + lane * 8;
    asm volatile("global_load_dwordx4 %0, %1, off\n\ts_waitcnt vmcnt(0)"
                 : "=v"(Breg[ks]) : "v"(p));
  }

  // ---- elementwise mapping: thread = (row erow, unit eu) of each group ----
  const int erow = tid >> 6, eu = tid & 63;
  float xwv[4], bias[4], addA[4], addB[4];
#pragma unroll
  for (int gt = 0; gt < 4; ++gt) {
    const int col = gt * 512 + U0 + eu;
    if (IS_DEC) {
      addA[gt] = xin[(RA + erow) * 2048 + col];
      addB[gt] = xin[(RB + erow) * 2048 + col];
      xwv[gt] = 0.f; bias[gt] = 0.f;
    } else {
      bias[gt] = wb[col];
      xwv[gt] = wa[col];
      addA[gt] = 0.f; addB[gt] = 0.f;
    }
  }
  // head weight slices: unit lane*8+q (full 512-unit row; same in all WGs)
  float wmu[8], wsg[8];
  if (IS_DEC) {
#pragma unroll
    for (int q = 0; q < 8; ++q) {
      wmu[q] = wa[lane * 8 + q];
      wsg[q] = wb[lane * 8 + q];
    }
  }

  float cA = 0.f, cB = 0.f;

  __shared__ __align__(16) f16 bufA[8 * 520];
  __shared__ __align__(16) f16 bufB[8 * 520];
  __shared__ __align__(16) float gatesL[8 * 264];

  // staging indices: 4 u64 per thread ([8 rows][256 u64] tile)
  int lrow[4], lcol[4], gidxA[4], gidxB[4];
#pragma unroll
  for (int i = 0; i < 4; ++i) {
    const int w = tid + i * 512;
    lrow[i] = w >> 8; lcol[i] = w & 255;
    gidxA[i] = (RA + lrow[i]) * 256 + lcol[i];
    gidxB[i] = (RB + lrow[i]) * 256 + lcol[i];
  }
  const u64* hb64 = (const u64*)hbuf;

  u64 wAr[4], wBr[4];
#pragma unroll
  for (int i = 0; i < 4; ++i)
    wAr[i] = __hip_atomic_load(hb64 + gidxA[i], __ATOMIC_RELAXED,
                               __HIP_MEMORY_SCOPE_AGENT);
  asm volatile("" ::: "memory");

  for (int t = 0; t < T_; ++t) {
    const int b0 = (t & 1) * 131072;
    const int b1 = ((t + 1) & 1) * 131072;
    const int c1 = ((t + 1) & 1) * 262144;
    const u32 gr = GB + (u32)t, gn = GB + (u32)t + 1u;

    // ================= A phase =================
    while (!(fresh_(wAr[0], gr) & fresh_(wAr[1], gr) &
             fresh_(wAr[2], gr) & fresh_(wAr[3], gr))) {
#pragma unroll
      for (int i = 0; i < 4; ++i)
        wAr[i] = __hip_atomic_load(hb64 + b0 + gidxA[i], __ATOMIC_RELAXED,
                                   __HIP_MEMORY_SCOPE_AGENT);
    }
#pragma unroll
    for (int i = 0; i < 4; ++i)
      *(u32*)&bufA[lrow[i] * 520 + lcol[i] * 2] = packh_(wAr[i]);
    __syncthreads();  // BAR1

    // issue B(t) prefetch (producer stored ~1 phase ago)
#pragma unroll
    for (int i = 0; i < 4; ++i)
      wBr[i] = __hip_atomic_load(hb64 + b0 + gidxB[i], __ATOMIC_RELAXED,
                                 __HIP_MEMORY_SCOPE_AGENT);
    asm volatile("" ::: "memory");

    // ---- decoder heads for output t-1, rows RA+wave (from staged bufA) ----
    if (IS_DEC && t >= 1) {
      const f16x8 hv = *(const f16x8*)&bufA[wave * 520 + lane * 8];
      float smu = 0.f, ssg = 0.f;
#pragma unroll
      for (int q = 0; q < 8; ++q) {
        const float hq = (float)hv[q];
        smu += hq * wmu[q]; ssg += hq * wsg[q];
      }
#pragma unroll
      for (int o = 32; o; o >>= 1) {
        smu += __shfl_xor(smu, o); ssg += __shfl_xor(ssg, o);
      }
      if (lane == 0) {
        accmu[(RA + wave) * 512 + (t - 1)] = smu;
        accsg[(RA + wave) * 512 + (t - 1)] = ssg;
      }
    }

    {
      f32x16 acc;
#pragma unroll
      for (int q = 0; q < 16; ++q) acc[q] = 0.f;
#pragma unroll
      for (int ks = 0; ks < 32; ++ks) {
        f16x8 a = *(const f16x8*)&bufA[(lane & 7) * 520 + ks * 16 + khalf * 8];
        acc = __builtin_amdgcn_mfma_f32_32x32x16_f16(a, Breg[ks], acc, 0, 0, 0);
      }
#pragma unroll
      for (int r = 0; r < 4; ++r)
        gatesL[(r + 4 * khalf) * 264 + wave * 32 + ccol] = acc[r];
    }
    __syncthreads();  // BAR2

    {  // ---- ew A ----
      const float4 g4 = *(const float4*)&gatesL[erow * 264 + (eu >> 3) * 32 + (eu & 7) * 4];
      float ga0, ga1, ga2, ga3;
      if (IS_DEC) {
        ga0 = g4.x + addA[0]; ga1 = g4.y + addA[1];
        ga2 = g4.z + addA[2]; ga3 = g4.w + addA[3];
      } else {
        const float xv = xin[(RA + erow) * T_ + t];
        ga0 = g4.x + bias[0] + xv * xwv[0];
        ga1 = g4.y + bias[1] + xv * xwv[1];
        ga2 = g4.z + bias[2] + xv * xwv[2];
        ga3 = g4.w + bias[3] + xv * xwv[3];
      }
      const float cn = sigm_(ga1) * cA + sigm_(ga0) * tanh_(ga2);
      cA = cn;
      const float hn = sigm_(ga3) * tanh_(cn);
      union { f16 h; unsigned short u; } hc; hc.h = (f16)hn;
      __hip_atomic_store(hbuf + c1 + (RA + erow) * 512 + U0 + eu,
                         (gn << 16) | (u32)hc.u, __ATOMIC_RELAXED,
                         __HIP_MEMORY_SCOPE_AGENT);
    }

    // ================= B phase =================
    while (!(fresh_(wBr[0], gr) & fresh_(wBr[1], gr) &
             fresh_(wBr[2], gr) & fresh_(wBr[3], gr))) {
#pragma unroll
      for (int i = 0; i < 4; ++i)
        wBr[i] = __hip_atomic_load(hb64 + b0 + gidxB[i], __ATOMIC_RELAXED,
                                   __HIP_MEMORY_SCOPE_AGENT);
    }
#pragma unroll
    for (int i = 0; i < 4; ++i)
      *(u32*)&bufB[lrow[i] * 520 + lcol[i] * 2] = packh_(wBr[i]);
    __syncthreads();  // BAR3

    // issue A(t+1) prefetch
#pragma unroll
    for (int i = 0; i < 4; ++i)
      wAr[i] = __hip_atomic_load(hb64 + b1 + gidxA[i], __ATOMIC_RELAXED,
                                 __HIP_MEMORY_SCOPE_AGENT);
    asm volatile("" ::: "memory");

    // ---- decoder heads for output t-1, rows RB+wave (from staged bufB) ----
    if (IS_DEC && t >= 1) {
      const f16x8 hv = *(const f16x8*)&bufB[wave * 520 + lane * 8];
      float smu = 0.f, ssg = 0.f;
#pragma unroll
      for (int q = 0; q < 8; ++q) {
        const float hq = (float)hv[q];
        smu += hq * wmu[q]; ssg += hq * wsg[q];
      }
#pragma unroll
      for (int o = 32; o; o >>= 1) {
        smu += __shfl_xor(smu, o); ssg += __shfl_xor(ssg, o);
      }
      if (lane == 0) {
        accmu[(RB + wave) * 512 + (t - 1)] = smu;
        accsg[(RB + wave) * 512 + (t - 1)] = ssg;
      }
    }

    {
      f32x16 acc;
#pragma unroll
      for (int q = 0; q < 16; ++q) acc[q] = 0.f;
#pragma unroll
      for (int ks = 0; ks < 32; ++ks) {
        f16x8 a = *(const f16x8*)&bufB[(lane & 7) * 520 + ks * 16 + khalf * 8];
        acc = __builtin_amdgcn_mfma_f32_32x32x16_f16(a, Breg[ks], acc, 0, 0, 0);
      }
#pragma unroll
      for (int r = 0; r < 4; ++r)
        gatesL[(r + 4 * khalf) * 264 + wave * 32 + ccol] = acc[r];
    }
    __syncthreads();  // BAR4

    {  // ---- ew B ----
      const float4 g4 = *(const float4*)&gatesL[erow * 264 + (eu >> 3) * 32 + (eu & 7) * 4];
      float ga0, ga1, ga2, ga3;
      if (IS_DEC) {
        ga0 = g4.x + addB[0]; ga1 = g4.y + addB[1];
        ga2 = g4.z + addB[2]; ga3 = g4.w + addB[3];
      } else {
        const float xv = xin[(RB + erow) * T_ + t];
        ga0 = g4.x + bias[0] + xv * xwv[0];
        ga1 = g4.y + bias[1] + xv * xwv[1];
        ga2 = g4.z + bias[2] + xv * xwv[2];
        ga3 = g4.w + bias[3] + xv * xwv[3];
      }
      const float cn = sigm_(ga1) * cB + sigm_(ga0) * tanh_(ga2);
      cB = cn;
      const float hn = sigm_(ga3) * tanh_(cn);
      union { f16 h; unsigned short u; } hc; hc.h = (f16)hn;
      __hip_atomic_store(hbuf + c1 + (RB + erow) * 512 + U0 + eu,
                         (gn << 16) | (u32)hc.u, __ATOMIC_RELAXED,
                         __HIP_MEMORY_SCOPE_AGENT);
    }
  }
}

// ---------------------------------------------------------------------------
// Decoder tail: mu/sg[., 511] from final h (buffer 0).
// ---------------------------------------------------------------------------
__global__ void dec_tail(const u32* __restrict__ hbuf, const float* __restrict__ dmuW,
                         const float* __restrict__ dstdW, float* __restrict__ accmu,
                         float* __restrict__ accsg) {
  const int r = blockIdx.x, lane = threadIdx.x;  // 64 threads
  float smu = 0.f, ssg = 0.f;
#pragma unroll
  for (int q = 0; q < 8; ++q) {
    union { unsigned short u; f16 h; } c;
    c.u = (unsigned short)(hbuf[r * 512 + lane * 8 + q] & 0xffffu);
    const float hq = (float)c.h;
    smu += hq * dmuW[lane * 8 + q];
    ssg += hq * dstdW[lane * 8 + q];
  }
#pragma unroll
  for (int o = 32; o; o >>= 1) {
    smu += __shfl_xor(smu, o); ssg += __shfl_xor(ssg, o);
  }
  if (lane == 0) {
    accmu[r * 512 + 511] = smu;
    accsg[r * 512 + 511] = ssg;
  }
}

// ---------------------------------------------------------------------------
__global__ void enc_heads(const u32* __restrict__ h0, const float* __restrict__ emuW,
                          const float* __restrict__ emub, const float* __restrict__ estdW,
                          const float* __restrict__ estdb, float* __restrict__ out,
                          float* __restrict__ z) {
  const int b = blockIdx.x, tid = threadIdx.x;
  __shared__ float hrow[512];
  for (int k = tid; k < 512; k += 128) {
    union { unsigned short u; f16 h; } c;
    c.u = (unsigned short)(h0[b * 512 + k] & 0xffffu);
    hrow[k] = (float)c.h;
  }
  __syncthreads();
  const int head = tid >> 6, l = tid & 63;
  const float* W = head ? estdW : emuW;
  float a = 0.f;
#pragma unroll 8
  for (int k = 0; k < 512; ++k) a += hrow[k] * W[k * 64 + l];
  if (head == 0) {
    const float v = a + emub[l];
    out[OFF_MU_ENC + b * 64 + l] = v;
    z[b * 64 + l] = v;
  } else {
    out[OFF_SG_ENC + b * 64 + l] = softplus_(a + estdb[l]);
  }
}

// ---------------------------------------------------------------------------
__global__ void dec_prep(const float* __restrict__ z, const float* __restrict__ dfsW,
                         const float* __restrict__ dfsb, const float* __restrict__ decW,
                         const float* __restrict__ decb, u32* __restrict__ hbuf,
                         float* __restrict__ zin) {
  const int b = blockIdx.x, tid = threadIdx.x;
  __shared__ float zl[64];
  if (tid < 64) zl[tid] = z[b * 64 + tid];
  __syncthreads();
  for (int c = tid; c < 512; c += 256) {
    float a = dfsb[c];
#pragma unroll
    for (int l = 0; l < 64; ++l) a += zl[l] * dfsW[l * 512 + c];
    union { f16 h; unsigned short u; } hc; hc.h = (f16)tanh_(a);
    hbuf[b * 512 + c] = (0x8000u << 16) | (u32)hc.u;
  }
  for (int c = tid; c < 2048; c += 256) {
    float a = decb[c];
#pragma unroll
    for (int l = 0; l < 64; ++l) a += zl[l] * decW[l * 2048 + c];
    zin[b * 2048 + c] = a;
  }
}

// ---------------------------------------------------------------------------
__global__ void finalize_k(const float* __restrict__ accmu, const float* __restrict__ accsg,
                           const float* __restrict__ dmub, const float* __restrict__ dstdb,
                           float* __restrict__ out) {
  const int i = blockIdx.x * 256 + threadIdx.x;
  out[i] = accmu[i] + dmub[0];
  out[OFF_SG_DEC + i] = softplus_(accsg[i] + dstdb[0]);
}

// ---------------------------------------------------------------------------
extern "C" void kernel_launch(void* const* d_in, const int* in_sizes, int n_in,
                              void* d_out, int out_size, void* d_ws, size_t ws_size,
                              hipStream_t stream) {
  (void)in_sizes; (void)n_in; (void)out_size; (void)ws_size;
  const float* x     = (const float*)d_in[0];
  const float* encW  = (const float*)d_in[1];
  const float* encU  = (const float*)d_in[2];
  const float* encb  = (const float*)d_in[3];
  const float* emuW  = (const float*)d_in[4];
  const float* emub  = (const float*)d_in[5];
  const float* estdW = (const float*)d_in[6];
  const float* estdb = (const float*)d_in[7];
  const float* dfsW  = (const float*)d_in[8];
  const float* dfsb  = (const float*)d_in[9];
  const float* decW  = (const float*)d_in[10];
  const float* decU  = (const float*)d_in[11];
  const float* decb  = (const float*)d_in[12];
  const float* dmuW  = (const float*)d_in[13];
  const float* dmub  = (const float*)d_in[14];
  const float* dstdW = (const float*)d_in[15];
  const float* dstdb = (const float*)d_in[16];

  char* ws = (char*)d_ws;
  u32*   hbuf  = (u32*)(ws + 0);                   // 2 MB: [2][512][512] u32
  float* accmu = (float*)(ws + (2u << 20));        // 1 MB
  float* accsg = (float*)(ws + (3u << 20));        // 1 MB
  f16*   UpkE  = (f16*)(ws + (4u << 20));          // 2 MB (dead after encoder)
  float* zin   = (float*)(ws + (4u << 20));        // 4 MB (overlays UpkE)
  f16*   UpkD  = (f16*)(ws + (8u << 20));          // 2 MB
  float* z     = (float*)(ws + (10u << 20));       // 128 KB
  float* out   = (float*)d_out;

  // zero hbuf (gen tags) every launch; acc fully rewritten by heads+tail.
  hipMemsetAsync(d_ws, 0, 2u << 20, stream);

  hipLaunchKernelGGL(pack_U, dim3(4096), dim3(256), 0, stream, encU, UpkE);
  hipLaunchKernelGGL(pack_U, dim3(4096), dim3(256), 0, stream, decU, UpkD);

  hipLaunchKernelGGL((lstm_rec<0>), dim3(256), dim3(512), 0, stream,
                     UpkE, x, encW, encb, hbuf, (float*)nullptr, (float*)nullptr);
  hipLaunchKernelGGL(enc_heads, dim3(512), dim3(128), 0, stream,
                     hbuf, emuW, emub, estdW, estdb, out, z);
  hipLaunchKernelGGL(dec_prep, dim3(512), dim3(256), 0, stream,
                     z, dfsW, dfsb, decW, decb, hbuf, zin);
  hipLaunchKernelGGL((lstm_rec<1>), dim3(256), dim3(512), 0, stream,
                     UpkD, zin, dmuW, dstdW, hbuf, accmu, accsg);
  hipLaunchKernelGGL(dec_tail, dim3(512), dim3(64), 0, stream,
                     hbuf, dmuW, dstdW, accmu, accsg);
  hipLaunchKernelGGL(finalize_k, dim3(1024), dim3(256), 0, stream,
                     accmu, accsg, dmub, dstdb, out);
}

// Round 10
// 4233.160 us; speedup vs baseline: 2.1282x; 1.1810x over previous
//
#include <hip/hip_runtime.h>

// ---------------------------------------------------------------------------
// VRAE LSTM: B=512, T=512, HE=HD=512, L=64.
// Round 10 = round-5 structure (measured-best decoder, 3.1us/step) with the
// encoder's per-step scattered x-gather replaced by one-time LDS staging.
// 32 groups (16 rows) x 8 WGs (64 units, 512 thr, 8 waves). U packed f16 in
// ws, asm-loaded (resident). h: f16 [2][512][512] double buffer via relaxed
// agent atomics; sync = store-drain + per-WG flag + 8-flag s_sleep poll.
// ---------------------------------------------------------------------------

#define B_   512
#define T_   512
#define H_   512
#define NGR  32   // groups
#define WPG  8    // WGs per group
#define RPG  16   // batch rows per group
#define UPW  64   // units per WG

typedef _Float16 f16;
typedef _Float16 f16x8 __attribute__((ext_vector_type(8)));
typedef _Float16 f16x4 __attribute__((ext_vector_type(4)));
typedef float f32x16 __attribute__((ext_vector_type(16)));
typedef unsigned long long u64;

// d_out floats: mu_dec[512*512] | sg_dec[512*512] | mu_enc[512*64] | sg_enc[512*64]
#define OFF_SG_DEC 262144
#define OFF_MU_ENC 524288
#define OFF_SG_ENC 557056

__device__ __forceinline__ float sigm_(float x) { return 1.f / (1.f + __expf(-x)); }
__device__ __forceinline__ float tanh_(float x) {
  float t = fabsf(x);
  float e = __expf(2.f * t);
  float r = 1.f - 2.f / (e + 1.f);
  return x < 0.f ? -r : r;
}
__device__ __forceinline__ float softplus_(float x) {
  return fmaxf(x, 0.f) + log1pf(__expf(-fabsf(x)));
}

// ---------------------------------------------------------------------------
// Pack U [512][2048] f32 -> f16 fragment order:
// Upk[(((wg*8+w)*32+ks)<<9) + lane*8 + j] = U[ks*16+(lane>>5)*8+j][gcol],
//   gcol = gate*512 + wg*64 + w*8 + uu, uu=(lane&31)>>2, gate=lane&3.
// ---------------------------------------------------------------------------
__global__ void pack_U(const float* __restrict__ U, f16* __restrict__ Upk) {
  const int e = blockIdx.x * 256 + threadIdx.x;  // 2^20 elements exactly
  const int j = e & 7, lane = (e >> 3) & 63, ks = (e >> 9) & 31;
  const int w = (e >> 14) & 7, wg = (e >> 17) & 7;
  const int ccol = lane & 31, khalf = lane >> 5;
  const int uu = ccol >> 2, gate = ccol & 3;
  const int k = ks * 16 + khalf * 8 + j;
  const int gcol = gate * 512 + wg * UPW + w * 8 + uu;
  Upk[e] = (f16)U[k * 2048 + gcol];
}

// ---------------------------------------------------------------------------
// IS_DEC=0: xin=[B][T] input (LDS-staged once), wa=enc_W, wb=enc_b
// IS_DEC=1: xin=zin [B][2048] incl bias, wa=dmu_W, wb=dstd_W
// hbuf: [2][512][512] f16 double-buffered h; flags: [32 g][8 wg][32 ints]
// ---------------------------------------------------------------------------
template <int IS_DEC>
__global__ void __launch_bounds__(512, 1)
lstm_rec(const f16* __restrict__ Upk,
         const float* __restrict__ xin,
         const float* __restrict__ wa,
         const float* __restrict__ wb,
         f16* __restrict__ hbuf,
         float* __restrict__ accmu,
         float* __restrict__ accsg,
         int* __restrict__ flags) {
  const int bid = blockIdx.x;
  // XCD-local: a group's 8 WGs share bid%8 -> one XCD.
  const int wg = (bid >> 3) & 7;
  const int g = (bid & 7) * 4 + (bid >> 6);  // 0..31
  const int tid = threadIdx.x;
  const int wave = tid >> 6, lane = tid & 63;
  const int R0 = g * RPG;    // global batch-row base
  const int U0 = wg * UPW;   // unit base

  // ---- Breg from packed U: asm loads (non-remat, resident) ----------------
  const int ccol = lane & 31, khalf = lane >> 5;
  f16x8 Breg[32];
#pragma unroll
  for (int ks = 0; ks < 32; ++ks) {
    const f16* p = Upk + (((wg * 8 + wave) * 32 + ks) << 9) + lane * 8;
    asm volatile("global_load_dwordx4 %0, %1, off\n\ts_waitcnt vmcnt(0)"
                 : "=v"(Breg[ks]) : "v"(p));
  }

  // ---- per-thread elementwise mapping (tid<256 active) --------------------
  const int row = tid >> 4;        // 0..15 for active threads
  const int q = (tid & 15) * 4;    // first of 4 units
  float addv[16], xw[16], dmur[4], dstdr[4];
  if (tid < 256) {
#pragma unroll
    for (int m = 0; m < 4; ++m) {
#pragma unroll
      for (int gt = 0; gt < 4; ++gt) {
        const int col = gt * 512 + U0 + q + m;
        if (IS_DEC) {
          addv[m * 4 + gt] = xin[(R0 + row) * 2048 + col];
          xw[m * 4 + gt] = 0.f;
        } else {
          addv[m * 4 + gt] = wb[col];
          xw[m * 4 + gt] = wa[col];
        }
      }
      if (IS_DEC) {
        dmur[m] = wa[U0 + q + m];
        dstdr[m] = wb[U0 + q + m];
      } else {
        dmur[m] = 0.f;
        dstdr[m] = 0.f;
      }
    }
  }

  float cst[4] = {0.f, 0.f, 0.f, 0.f};

  __shared__ __align__(16) f16 hstage[RPG * 536];   // 17,152 B
  __shared__ float gatesLds[RPG * 260];             // 16,640 B
  __shared__ float pmuLds[RPG * 17];
  __shared__ float psgLds[RPG * 17];
  __shared__ float xl[RPG * 516];                   // 33,024 B (encoder x)

  if (!IS_DEC) {
    // one-time coalesced stage of x[R0..R0+16)[0..512) -> LDS
#pragma unroll
    for (int i = 0; i < 16; ++i) {
      const int idx = tid + i * 512;
      const int r = idx >> 9, c2 = idx & 511;
      xl[r * 516 + c2] = xin[(R0 + r) * T_ + c2];
    }
    __syncthreads();
  }

  const int hrow = lane & 15;  // MFMA A row
  int* const myflag = &flags[(g * WPG + wg) * 32];
  int* const grpflags = &flags[(g * WPG) * 32];

  for (int t = 0; t < T_; ++t) {
    // ------------------ stage group h tile (16KB) -> LDS -----------------
    const u64* hsrc64 = (const u64*)(hbuf + (t & 1) * (B_ * H_) + R0 * H_);
#pragma unroll
    for (int i = 0; i < 4; ++i) {
      const int w = tid + i * 512;  // 2048 u64 total; 128 u64 per row
      const int r = w >> 7, c8 = w & 127;
      u64 v = __hip_atomic_load(hsrc64 + w, __ATOMIC_RELAXED,
                                __HIP_MEMORY_SCOPE_AGENT);
      *(u64*)&hstage[r * 536 + c8 * 4] = v;
    }
    __syncthreads();

    // ------------------ gates = h @ U (MFMA 32x32x16, B in regs) ---------
    f32x16 acc;
#pragma unroll
    for (int j = 0; j < 16; ++j) acc[j] = 0.f;
#pragma unroll
    for (int ks = 0; ks < 32; ++ks) {
      f16x8 a = *(const f16x8*)&hstage[hrow * 536 + ks * 16 + khalf * 8];
      acc = __builtin_amdgcn_mfma_f32_32x32x16_f16(a, Breg[ks], acc, 0, 0, 0);
    }
    // C rows 0..15 live in regs 0..7 (row=(r&3)+8*(r>>2)+4*khalf)
#pragma unroll
    for (int r = 0; r < 8; ++r) {
      const int orow = (r & 3) + 8 * (r >> 2) + 4 * khalf;
      gatesLds[orow * 260 + wave * 32 + ccol] = acc[r];
    }
    __syncthreads();

    // ------------------ elementwise LSTM update (tid<256) ----------------
    union { f16x4 h4; u64 u; } cv;
    if (tid < 256) {
      float xv = 0.f;
      if (!IS_DEC) xv = xl[row * 516 + t];
      float hn[4];
#pragma unroll
      for (int m = 0; m < 4; ++m) {
        float ga[4];
#pragma unroll
        for (int gt = 0; gt < 4; ++gt) {
          float v = gatesLds[row * 260 + (q + m) * 4 + gt] + addv[m * 4 + gt];
          if (!IS_DEC) v += xv * xw[m * 4 + gt];
          ga[gt] = v;
        }
        const float iv = sigm_(ga[0]);
        const float fv = sigm_(ga[1]);
        const float gv = tanh_(ga[2]);
        const float ov = sigm_(ga[3]);
        const float cn = fv * cst[m] + iv * gv;
        cst[m] = cn;
        hn[m] = ov * tanh_(cn);
      }
#pragma unroll
      for (int m = 0; m < 4; ++m) cv.h4[m] = (f16)hn[m];
      f16* hdst = hbuf + ((t + 1) & 1) * (B_ * H_) + (R0 + row) * H_ + U0 + q;
      __hip_atomic_store((u64*)hdst, cv.u, __ATOMIC_RELAXED,
                         __HIP_MEMORY_SCOPE_AGENT);
      if (IS_DEC) {
        float pmu = 0.f, psg = 0.f;
#pragma unroll
        for (int m = 0; m < 4; ++m) {
          pmu += (float)cv.h4[m] * dmur[m];
          psg += (float)cv.h4[m] * dstdr[m];
        }
        pmuLds[row * 17 + (tid & 15)] = pmu;
        psgLds[row * 17 + (tid & 15)] = psg;
      }
    }

    // ------------------ release: h stores acked at LLC, then flag --------
    asm volatile("s_waitcnt vmcnt(0)" ::: "memory");
    __syncthreads();
    if (t + 1 < T_ && tid == 0)
      __hip_atomic_store(myflag, t + 1, __ATOMIC_RELAXED,
                         __HIP_MEMORY_SCOPE_AGENT);

    if (IS_DEC) {  // head partial reduction, off the critical path
      if (tid < RPG) {
        float s = 0.f;
#pragma unroll
        for (int j = 0; j < 16; ++j) s += pmuLds[tid * 17 + j];
        unsafeAtomicAdd(&accmu[(R0 + tid) * T_ + t], s);
      } else if (tid < 2 * RPG) {
        const int rr = tid - RPG;
        float s = 0.f;
#pragma unroll
        for (int j = 0; j < 16; ++j) s += psgLds[rr * 17 + j];
        unsafeAtomicAdd(&accsg[(R0 + rr) * T_ + t], s);
      }
    }

    // ------------------ group barrier: poll 8 flags (relaxed + sleep) ----
    if (t + 1 < T_) {
      if (tid < WPG) {
        while (__hip_atomic_load(&grpflags[tid * 32], __ATOMIC_RELAXED,
                                 __HIP_MEMORY_SCOPE_AGENT) < t + 1) {
          asm volatile("s_sleep 1");
        }
      }
      __syncthreads();
    }
  }
}

// ---------------------------------------------------------------------------
__global__ void enc_heads(const f16* __restrict__ h0, const float* __restrict__ emuW,
                          const float* __restrict__ emub, const float* __restrict__ estdW,
                          const float* __restrict__ estdb, float* __restrict__ out,
                          float* __restrict__ z) {
  const int b = blockIdx.x, tid = threadIdx.x;
  __shared__ float hrow[512];
  for (int k = tid; k < 512; k += 128)
    hrow[k] = (float)h0[b * H_ + k];
  __syncthreads();
  const int head = tid >> 6, l = tid & 63;
  const float* W = head ? estdW : emuW;
  float a = 0.f;
#pragma unroll 8
  for (int k = 0; k < 512; ++k) a += hrow[k] * W[k * 64 + l];
  if (head == 0) {
    const float v = a + emub[l];
    out[OFF_MU_ENC + b * 64 + l] = v;
    z[b * 64 + l] = v;
  } else {
    out[OFF_SG_ENC + b * 64 + l] = softplus_(a + estdb[l]);
  }
}

// ---------------------------------------------------------------------------
__global__ void dec_prep(const float* __restrict__ z, const float* __restrict__ dfsW,
                         const float* __restrict__ dfsb, const float* __restrict__ decW,
                         const float* __restrict__ decb, f16* __restrict__ hbuf,
                         float* __restrict__ zin) {
  const int b = blockIdx.x, tid = threadIdx.x;
  __shared__ float zl[64];
  if (tid < 64) zl[tid] = z[b * 64 + tid];
  __syncthreads();
  for (int c = tid; c < 512; c += 256) {
    float a = dfsb[c];
#pragma unroll
    for (int l = 0; l < 64; ++l) a += zl[l] * dfsW[l * 512 + c];
    hbuf[b * H_ + c] = (f16)tanh_(a);
  }
  for (int c = tid; c < 2048; c += 256) {
    float a = decb[c];
#pragma unroll
    for (int l = 0; l < 64; ++l) a += zl[l] * decW[l * 2048 + c];
    zin[b * 2048 + c] = a;
  }
}

// ---------------------------------------------------------------------------
__global__ void finalize_k(const float* __restrict__ accmu, const float* __restrict__ accsg,
                           const float* __restrict__ dmub, const float* __restrict__ dstdb,
                           float* __restrict__ out) {
  const int i = blockIdx.x * 256 + threadIdx.x;
  out[i] = accmu[i] + dmub[0];
  out[OFF_SG_DEC + i] = softplus_(accsg[i] + dstdb[0]);
}

// ---------------------------------------------------------------------------
extern "C" void kernel_launch(void* const* d_in, const int* in_sizes, int n_in,
                              void* d_out, int out_size, void* d_ws, size_t ws_size,
                              hipStream_t stream) {
  (void)in_sizes; (void)n_in; (void)out_size; (void)ws_size;
  const float* x     = (const float*)d_in[0];
  const float* encW  = (const float*)d_in[1];
  const float* encU  = (const float*)d_in[2];
  const float* encb  = (const float*)d_in[3];
  const float* emuW  = (const float*)d_in[4];
  const float* emub  = (const float*)d_in[5];
  const float* estdW = (const float*)d_in[6];
  const float* estdb = (const float*)d_in[7];
  const float* dfsW  = (const float*)d_in[8];
  const float* dfsb  = (const float*)d_in[9];
  const float* decW  = (const float*)d_in[10];
  const float* decb  = (const float*)d_in[12];
  const float* decU  = (const float*)d_in[11];
  const float* dmuW  = (const float*)d_in[13];
  const float* dmub  = (const float*)d_in[14];
  const float* dstdW = (const float*)d_in[15];
  const float* dstdb = (const float*)d_in[16];

  char* ws = (char*)d_ws;
  f16* hbuf    = (f16*)(ws + 0);                        // 1 MB [2][512][512]
  float* accmu = (float*)(ws + (1u << 20));             // 1 MB
  float* accsg = (float*)(ws + (2u << 20));             // 1 MB
  int* flags   = (int*)(ws + (3u << 20));               // 64 KB (2 phases)
  f16* UpkE    = (f16*)(ws + (3u << 20) + 65536);       // 2 MB (dead post-enc)
  float* zin   = (float*)(ws + (3u << 20) + 65536);     // 4 MB (overlays UpkE)
  f16* UpkD    = (f16*)(ws + (7u << 20) + 65536);       // 2 MB
  float* z     = (float*)(ws + (9u << 20) + 65536);     // 128 KB
  float* out   = (float*)d_out;

  // zero hbuf/acc/flags (must be re-done every launch)
  hipMemsetAsync(d_ws, 0, (3u << 20) + 65536, stream);

  hipLaunchKernelGGL(pack_U, dim3(4096), dim3(256), 0, stream, encU, UpkE);
  hipLaunchKernelGGL(pack_U, dim3(4096), dim3(256), 0, stream, decU, UpkD);

  hipLaunchKernelGGL((lstm_rec<0>), dim3(256), dim3(512), 0, stream,
                     UpkE, x, encW, encb, hbuf, (float*)nullptr, (float*)nullptr,
                     flags);
  hipLaunchKernelGGL(enc_heads, dim3(512), dim3(128), 0, stream,
                     hbuf, emuW, emub, estdW, estdb, out, z);
  hipLaunchKernelGGL(dec_prep, dim3(512), dim3(256), 0, stream,
                     z, dfsW, dfsb, decW, decb, hbuf, zin);
  hipLaunchKernelGGL((lstm_rec<1>), dim3(256), dim3(512), 0, stream,
                     UpkD, zin, dmuW, dstdW, hbuf, accmu, accsg, flags + 8192);
  hipLaunchKernelGGL(finalize_k, dim3(1024), dim3(256), 0, stream,
                     accmu, accsg, dmub, dstdb, out);
}